// Round 7
// baseline (249.998 us; speedup 1.0000x reference)
//
#include <hip/hip_runtime.h>

// WindowMSA fused kernel for MI355X (gfx950).
// One block = one window (B=4096). 4 waves = 4 heads, each wave owns its head.
// R10: R9 with (a) gT restored to padded [64][40] (80B row stride, no XOR) --
//      R7's [64][32]^XOR gT had inherent 4-way conflicts (12.58M cycles,
//      3072/block, ~16% of CU time on the LDS pipe); [64][40] is conflict-free
//      for every access here and deletes the XOR address math;
//      (b) O now lands in the wave's own gT slab (P dead after PV), V^T slab
//      in gA is never overwritten; (c) exp2-domain softmax: log2(e) folded
//      into the Q scale, v_exp_f32 directly (-64 v_mul/wave).
//      LDS 36,864 B => 4 blocks/CU at (256,4); 3 barriers total.

typedef __bf16 bf16_t;
typedef __bf16 bf8v  __attribute__((ext_vector_type(8)));
typedef __bf16 bf4v  __attribute__((ext_vector_type(4)));
typedef float  f4v   __attribute__((ext_vector_type(4)));

// (1/sqrt(32)) * log2(e): QK^T logits land in exp2 domain.
#define QK_SCALE_LOG2E 0.25503487f

__device__ __forceinline__ f4v mfma16(bf8v a, bf8v b, f4v c) {
  return __builtin_amdgcn_mfma_f32_16x16x32_bf16(a, b, c, 0, 0, 0);
}

// ---------------- prep ----------------
// wq: [t<24][kt<4][lane<64][j<8]  = bf16(qkv_w[t*16+(l&15)][kt*32+(l>>4)*8+j])
// wp: [t<8 ][kt<4][lane<64][j<8]  = bf16(proj_w[...same...])
// ebias: [h<4][t<16][ln<64][r<4] f32 = exp(bias) at query n=16*(t>>2)+(ln&15),
//        key m=16*(t&3)+4*(ln>>4)+r; 1.0 outside valid range. 64 KB, w-indep.
// maskq: [w<64][ln<64] uint2; bit t*4+r = (key valid AND not masked).
__global__ void prep_kernel(const float* __restrict__ mask,
                            const float* __restrict__ qkv_w,
                            const float* __restrict__ proj_w,
                            const float* __restrict__ bias_table,
                            bf16_t* __restrict__ wq,
                            bf16_t* __restrict__ wp,
                            float* __restrict__ ebias,
                            uint2* __restrict__ maskq) {
  const int stride = gridDim.x * blockDim.x;
  const int tid0 = blockIdx.x * blockDim.x + threadIdx.x;
  for (int i = tid0; i < 24 * 4 * 64 * 8; i += stride) {
    int j = i & 7, l = (i >> 3) & 63, kt = (i >> 9) & 3, t = i >> 11;
    int n = t * 16 + (l & 15), k = kt * 32 + (l >> 4) * 8 + j;
    wq[i] = (bf16_t)qkv_w[n * 128 + k];
  }
  for (int i = tid0; i < 8 * 4 * 64 * 8; i += stride) {
    int j = i & 7, l = (i >> 3) & 63, kt = (i >> 9) & 3, t = i >> 11;
    int n = t * 16 + (l & 15), k = kt * 32 + (l >> 4) * 8 + j;
    wp[i] = (bf16_t)proj_w[n * 128 + k];
  }
  for (int i = tid0; i < 4 * 16 * 64 * 4; i += stride) {
    int r = i & 3, ln = (i >> 2) & 63, t = (i >> 8) & 15, h = i >> 12;
    int n = (t >> 2) * 16 + (ln & 15);
    int m = (t & 3) * 16 + (ln >> 4) * 4 + r;
    float v = 1.0f;
    if (n < 49 && m < 49) {
      int cn = 13 * (n / 7) + n % 7;
      int mm = 48 - m;
      int cm = 13 * (mm / 7) + mm % 7;
      v = __expf(bias_table[(cn + cm) * 4 + h]);
    }
    ebias[i] = v;
  }
  for (int i = tid0; i < 64 * 64; i += stride) {
    int ln = i & 63, w = i >> 6;
    unsigned lo = 0, hi = 0;
    for (int t = 0; t < 16; ++t) {
      int n = (t >> 2) * 16 + (ln & 15);
      for (int r = 0; r < 4; ++r) {
        int m = (t & 3) * 16 + (ln >> 4) * 4 + r;
        bool on = (m < 49) && (n >= 49 || mask[(w * 49 + n) * 49 + m] > -50.0f);
        int bit = t * 4 + r;
        if (on) { if (bit < 32) lo |= 1u << bit; else hi |= 1u << (bit - 32); }
      }
    }
    maskq[i] = make_uint2(lo, hi);
  }
}

// ---------------- fused window MSA ----------------
__global__ __launch_bounds__(256, 4) void msa_kernel(
    const float* __restrict__ x,
    const float* __restrict__ qkv_b,
    const float* __restrict__ proj_b,
    const bf16_t* __restrict__ wq,
    const bf16_t* __restrict__ wp,
    const float* __restrict__ ebias,
    const uint2* __restrict__ maskq,
    float* __restrict__ out) {
  // gA (16,384 B): As[64][128] bf16, 16B-block XOR-swizzle by (row&7)
  //   [conflict-free]. After barrier-2 aliased by per-head V^T[32][64]
  //   (16B-block XOR by d&7) [conflict-free]; V^T stays live through PV.
  // gT (4 x 5,120 B wave-private slabs): [64][40] padded, NO xor -- 80B row
  //   stride puts 16-row accesses on 8 distinct 16B slots (2-deep = free).
  //   Hosts, in order, K -> Q -> P(half0) -> P(half1) -> O. Proj reads all
  //   4 slabs after barrier-3.
  // Total 36,864 B => 4 blocks/CU.
  __shared__ __align__(16) bf16_t gA[8192];
  __shared__ __align__(16) bf16_t gT[4][2560];

#define VTP(hh, d, c) (gA + (hh) * 2048 + (d) * 64 + (((((c) >> 3) ^ ((d) & 7))) << 3) + ((c) & 7))
#define TTP(hh, row, c) (gT[hh] + (row) * 40 + (c))

  const int tid = threadIdx.x;
  const int wv  = tid >> 6;   // wave 0..3 == head
  const int ln  = tid & 63;
  const int l16 = ln & 15;
  const int l4  = ln >> 4;    // 0..3
  const int b   = blockIdx.x;
  const int w   = b & 63;     // mask window index
  const int h   = wv;

  // mask bits for this lane's (query,key) fragment positions — issue early.
  const uint2 mq = maskq[(w << 6) | ln];

  // ---- Phase 1: x -> As (bf16, swizzled), 16B writes, zero pad rows ----
  {
    const float4* xb = (const float4*)(x + (size_t)b * (49 * 128));
#pragma unroll
    for (int j = 0; j < 4; ++j) {
      int idx = j * 256 + tid;      // 0..1023
      int row = idx >> 4;
      int c8  = idx & 15;
      bf8v o;
      if (row < 49) {
        float4 u0 = xb[row * 32 + c8 * 2];
        float4 u1 = xb[row * 32 + c8 * 2 + 1];
        o = (bf8v){ (bf16_t)u0.x, (bf16_t)u0.y, (bf16_t)u0.z, (bf16_t)u0.w,
                    (bf16_t)u1.x, (bf16_t)u1.y, (bf16_t)u1.z, (bf16_t)u1.w };
      } else {
        o = (bf8v){ (bf16_t)0.f, (bf16_t)0.f, (bf16_t)0.f, (bf16_t)0.f,
                    (bf16_t)0.f, (bf16_t)0.f, (bf16_t)0.f, (bf16_t)0.f };
      }
      *(bf8v*)(gA + row * 128 + ((c8 ^ (row & 7)) << 3)) = o;
    }
  }
  __syncthreads();

  // ---- pass 1 (SWAPPED): Q^T_h, K^T_h = W @ X^T  (acc rows = channels) ----
  f4v acc[4][4];   // [ti: 0,1 = Q d-tiles; 2,3 = K d-tiles][mt]
#pragma unroll
  for (int ti = 0; ti < 4; ++ti)
#pragma unroll
    for (int mt = 0; mt < 4; ++mt) acc[ti][mt] = (f4v){0.f, 0.f, 0.f, 0.f};
#pragma unroll
  for (int kt = 0; kt < 4; ++kt) {
    bf8v bb[4];
#pragma unroll
    for (int ti = 0; ti < 4; ++ti) {
      int t = (ti < 2) ? (2 * h + ti) : (8 + 2 * h + (ti - 2));
      bb[ti] = *(const bf8v*)(wq + (((t * 4 + kt) * 64 + ln) << 3));
    }
#pragma unroll
    for (int mt = 0; mt < 4; ++mt) {
      int row = mt * 16 + l16;
      bf8v a = *(const bf8v*)(gA + row * 128 + ((((4 * kt + l4)) ^ (row & 7)) << 3));
#pragma unroll
      for (int ti = 0; ti < 4; ++ti)
        acc[ti][mt] = mfma16(bb[ti], a, acc[ti][mt]);
    }
  }

  // ---- K epilogue: transposed b64 stores -> K[tok][d]; kf frags ----
  bf8v kf[4], qf[4];
#pragma unroll
  for (int ti = 0; ti < 2; ++ti) {
    float4 kb = *(const float4*)(qkv_b + 128 + 32 * h + 16 * ti + 4 * l4);
#pragma unroll
    for (int mt = 0; mt < 4; ++mt) {
      f4v v = acc[2 + ti][mt];
      bf4v o = { (bf16_t)(v[0] + kb.x), (bf16_t)(v[1] + kb.y),
                 (bf16_t)(v[2] + kb.z), (bf16_t)(v[3] + kb.w) };
      *(bf4v*)TTP(h, mt * 16 + l16, ti * 16 + 4 * l4) = o;
    }
  }
#pragma unroll
  for (int mt = 0; mt < 4; ++mt)
    kf[mt] = *(const bf8v*)TTP(h, mt * 16 + l16, 8 * l4);

  // ---- Q epilogue (overwrites K copy; in-wave DS order); exp2-domain scale ----
#pragma unroll
  for (int ti = 0; ti < 2; ++ti) {
    float4 qb = *(const float4*)(qkv_b + 32 * h + 16 * ti + 4 * l4);
#pragma unroll
    for (int mt = 0; mt < 4; ++mt) {
      f4v v = acc[ti][mt];
      bf4v o = { (bf16_t)((v[0] + qb.x) * QK_SCALE_LOG2E),
                 (bf16_t)((v[1] + qb.y) * QK_SCALE_LOG2E),
                 (bf16_t)((v[2] + qb.z) * QK_SCALE_LOG2E),
                 (bf16_t)((v[3] + qb.w) * QK_SCALE_LOG2E) };
      *(bf4v*)TTP(h, mt * 16 + l16, ti * 16 + 4 * l4) = o;
    }
  }
#pragma unroll
  for (int mt = 0; mt < 4; ++mt)
    qf[mt] = *(const bf8v*)TTP(h, mt * 16 + l16, 8 * l4);

  // ---- pass 2: V_h, UNSWAPPED (acc rows = tokens, matches V^T epilogue) ----
  f4v vacc[2][4];
#pragma unroll
  for (int ti = 0; ti < 2; ++ti)
#pragma unroll
    for (int mt = 0; mt < 4; ++mt) vacc[ti][mt] = (f4v){0.f, 0.f, 0.f, 0.f};
#pragma unroll
  for (int kt = 0; kt < 4; ++kt) {
    bf8v bb2[2];
#pragma unroll
    for (int ti = 0; ti < 2; ++ti) {
      int t = 16 + 2 * h + ti;
      bb2[ti] = *(const bf8v*)(wq + (((t * 4 + kt) * 64 + ln) << 3));
    }
#pragma unroll
    for (int mt = 0; mt < 4; ++mt) {
      int row = mt * 16 + l16;
      bf8v a = *(const bf8v*)(gA + row * 128 + ((((4 * kt + l4)) ^ (row & 7)) << 3));
#pragma unroll
      for (int ti = 0; ti < 2; ++ti)
        vacc[ti][mt] = mfma16(a, bb2[ti], vacc[ti][mt]);   // X as A => rows=tok
    }
  }

  __syncthreads();   // barrier-2: all As reads done -> V^T may alias gA

  // ---- V^T epilogue: V^T[d = ti*16+l16][tok = mt*16+4*l4+r], b64 stores ----
#pragma unroll
  for (int ti = 0; ti < 2; ++ti) {
    float bias = qkv_b[256 + 32 * h + ti * 16 + l16];
#pragma unroll
    for (int mt = 0; mt < 4; ++mt) {
      bf4v o = { (bf16_t)(vacc[ti][mt][0] + bias), (bf16_t)(vacc[ti][mt][1] + bias),
                 (bf16_t)(vacc[ti][mt][2] + bias), (bf16_t)(vacc[ti][mt][3] + bias) };
      *(bf4v*)VTP(h, ti * 16 + l16, mt * 16 + 4 * l4) = o;
    }
  }

  // ---- QK^T + softmax in two key-halves (lg capped at 32 regs) ----
  // lane (l4,l16) reg r = P[query=16nt+l16][key=16mtk+4l4+r]
  const float* ebh = ebias + ((size_t)h << 12);   // [t][ln][4]
  bf4v pk[2][4];                                  // packed half-1 P (bf16)
#pragma unroll
  for (int half = 0; half < 2; ++half) {
    f4v lgh[2][4];
#pragma unroll
    for (int mtk2 = 0; mtk2 < 2; ++mtk2)
#pragma unroll
      for (int nt = 0; nt < 4; ++nt)
        lgh[mtk2][nt] = mfma16(kf[half * 2 + mtk2], qf[nt], (f4v){0.f, 0.f, 0.f, 0.f});
#pragma unroll
    for (int nt = 0; nt < 4; ++nt) {
#pragma unroll
      for (int mtk2 = 0; mtk2 < 2; ++mtk2) {
        const int t = nt * 4 + half * 2 + mtk2;
        float4 e = *(const float4*)(ebh + (((t << 6) | ln) << 2));
        unsigned bits = (t < 8) ? (mq.x >> (4 * t)) : (mq.y >> (4 * t - 32));
        f4v p;
        p[0] = (bits & 1u) ? __builtin_amdgcn_exp2f(lgh[mtk2][nt][0]) * e.x : 0.f;
        p[1] = (bits & 2u) ? __builtin_amdgcn_exp2f(lgh[mtk2][nt][1]) * e.y : 0.f;
        p[2] = (bits & 4u) ? __builtin_amdgcn_exp2f(lgh[mtk2][nt][2]) * e.z : 0.f;
        p[3] = (bits & 8u) ? __builtin_amdgcn_exp2f(lgh[mtk2][nt][3]) * e.w : 0.f;
        bf4v o = { (bf16_t)p[0], (bf16_t)p[1], (bf16_t)p[2], (bf16_t)p[3] };
        if (half == 0)
          *(bf4v*)TTP(h, nt * 16 + l16, mtk2 * 16 + 4 * l4) = o;   // over Q
        else
          pk[mtk2][nt] = o;
      }
    }
  }

  // ---- PV (SWAPPED): O^T = V^T @ P^T ; s = 1 @ P^T ; two key-halves ----
  const bf16_t one16 = (bf16_t)1.0f;
  const bf8v ones = { one16, one16, one16, one16, one16, one16, one16, one16 };
  f4v oc[2][4], sacc[4];
#pragma unroll
  for (int nt = 0; nt < 4; ++nt) {
    sacc[nt] = (f4v){0.f, 0.f, 0.f, 0.f};
#pragma unroll
    for (int dt = 0; dt < 2; ++dt) oc[dt][nt] = (f4v){0.f, 0.f, 0.f, 0.f};
  }
  {
    bf8v pf[4], vf[2];
#pragma unroll
    for (int nt = 0; nt < 4; ++nt) pf[nt] = *(const bf8v*)TTP(h, nt * 16 + l16, 8 * l4);
#pragma unroll
    for (int dt = 0; dt < 2; ++dt) vf[dt] = *(const bf8v*)VTP(h, dt * 16 + l16, 8 * l4);
#pragma unroll
    for (int dt = 0; dt < 2; ++dt)
#pragma unroll
      for (int nt = 0; nt < 4; ++nt) oc[dt][nt] = mfma16(vf[dt], pf[nt], oc[dt][nt]);
#pragma unroll
    for (int nt = 0; nt < 4; ++nt) sacc[nt] = mfma16(ones, pf[nt], sacc[nt]);
    // stage P half-1 over T (Q/P0 already consumed; in-wave DS order)
#pragma unroll
    for (int nt = 0; nt < 4; ++nt)
#pragma unroll
      for (int mtk2 = 0; mtk2 < 2; ++mtk2)
        *(bf4v*)TTP(h, nt * 16 + l16, mtk2 * 16 + 4 * l4) = pk[mtk2][nt];
#pragma unroll
    for (int nt = 0; nt < 4; ++nt) pf[nt] = *(const bf8v*)TTP(h, nt * 16 + l16, 8 * l4);
#pragma unroll
    for (int dt = 0; dt < 2; ++dt) vf[dt] = *(const bf8v*)VTP(h, dt * 16 + l16, 32 + 8 * l4);
#pragma unroll
    for (int dt = 0; dt < 2; ++dt)
#pragma unroll
      for (int nt = 0; nt < 4; ++nt) oc[dt][nt] = mfma16(vf[dt], pf[nt], oc[dt][nt]);
#pragma unroll
    for (int nt = 0; nt < 4; ++nt) sacc[nt] = mfma16(ones, pf[nt], sacc[nt]);
  }

  // ---- normalize + transposed b64 store: O[tok][d] into own gT slab ----
#pragma unroll
  for (int nt = 0; nt < 4; ++nt) {
    float inv = 1.0f / sacc[nt][0];
#pragma unroll
    for (int dt = 0; dt < 2; ++dt) {
      f4v v = oc[dt][nt];
      bf4v o = { (bf16_t)(v[0] * inv), (bf16_t)(v[1] * inv),
                 (bf16_t)(v[2] * inv), (bf16_t)(v[3] * inv) };
      *(bf4v*)TTP(h, nt * 16 + l16, dt * 16 + 4 * l4) = o;
    }
  }

  __syncthreads();   // barrier-3: O slabs -> proj

  // ---- proj GEMM (SWAPPED): rows = channels => float4 output stores ----
  {
    f4v pacc[4][2];   // [mt(token tile)][nj]; reg r = channel 4*l4+r within t
#pragma unroll
    for (int mt = 0; mt < 4; ++mt)
#pragma unroll
      for (int nj = 0; nj < 2; ++nj) pacc[mt][nj] = (f4v){0.f, 0.f, 0.f, 0.f};
#pragma unroll
    for (int kt = 0; kt < 4; ++kt) {
      bf8v bwv[2];
#pragma unroll
      for (int nj = 0; nj < 2; ++nj) {
        int t = wv * 2 + nj;
        bwv[nj] = *(const bf8v*)(wp + (((t * 4 + kt) * 64 + ln) << 3));
      }
#pragma unroll
      for (int mt = 0; mt < 4; ++mt) {
        bf8v a = *(const bf8v*)TTP(kt, mt * 16 + l16, 8 * l4);
#pragma unroll
        for (int nj = 0; nj < 2; ++nj)
          pacc[mt][nj] = mfma16(bwv[nj], a, pacc[mt][nj]);   // W as A => rows=chan
      }
    }
    float* ob = out + (size_t)b * (49 * 128);
#pragma unroll
    for (int nj = 0; nj < 2; ++nj) {
      int c0 = (wv * 2 + nj) * 16 + 4 * l4;
      float4 pb4 = *(const float4*)(proj_b + c0);
#pragma unroll
      for (int mt = 0; mt < 4; ++mt) {
        int tok = mt * 16 + l16;
        if (tok < 49) {
          f4v v = pacc[mt][nj];
          float4 o = make_float4(v[0] + pb4.x, v[1] + pb4.y,
                                 v[2] + pb4.z, v[3] + pb4.w);
          *(float4*)(ob + tok * 128 + c0) = o;
        }
      }
    }
  }
}

extern "C" void kernel_launch(void* const* d_in, const int* in_sizes, int n_in,
                              void* d_out, int out_size, void* d_ws, size_t ws_size,
                              hipStream_t stream) {
  const float* x          = (const float*)d_in[0];
  const float* mask       = (const float*)d_in[1];
  const float* qkv_w      = (const float*)d_in[2];
  const float* qkv_b      = (const float*)d_in[3];
  const float* proj_w     = (const float*)d_in[4];
  const float* proj_b     = (const float*)d_in[5];
  const float* bias_table = (const float*)d_in[6];

  char* ws = (char*)d_ws;
  bf16_t* wq    = (bf16_t*)ws;                    // 24*4*64*8 bf16 = 98304 B
  bf16_t* wp    = (bf16_t*)(ws + 98304);          // 8*4*64*8 bf16  = 32768 B
  float*  ebias = (float*)(ws + 131072);          // 4*16*64*4 f32  = 65536 B
  uint2*  maskq = (uint2*)(ws + 196608);          // 64*64 uint2    = 32768 B

  prep_kernel<<<1024, 256, 0, stream>>>(mask, qkv_w, proj_w, bias_table,
                                        wq, wp, ebias, maskq);
  msa_kernel<<<4096, 256, 0, stream>>>(x, qkv_b, proj_b, wq, wp, ebias, maskq,
                                       (float*)d_out);
}

// Round 8
// 235.939 us; speedup vs baseline: 1.0596x; 1.0596x over previous
//
#include <hip/hip_runtime.h>

// WindowMSA fused kernel for MI355X (gfx950).
// One block = one window (B=4096). 4 waves = 4 heads, each wave owns its head.
// R11: R10 with (a) rel-pos bias folded into the QK^T MFMA accumulator init
//      (log2-domain table as the C operand) -- deletes 64 v_mul/wave and moves
//      the 16 table loads off the softmax critical path; (b) s_setprio(1)
//      around MFMA clusters (4 desynced blocks/CU give the scheduler waves to
//      arbitrate). LDS 36,864 B => 4 blocks/CU at (256,4); 3 barriers total.

typedef __bf16 bf16_t;
typedef __bf16 bf8v  __attribute__((ext_vector_type(8)));
typedef __bf16 bf4v  __attribute__((ext_vector_type(4)));
typedef float  f4v   __attribute__((ext_vector_type(4)));

// (1/sqrt(32)) * log2(e): QK^T logits land in exp2 domain.
#define QK_SCALE_LOG2E 0.25503487f
#define LOG2E 1.4426950408889634f

__device__ __forceinline__ f4v mfma16(bf8v a, bf8v b, f4v c) {
  return __builtin_amdgcn_mfma_f32_16x16x32_bf16(a, b, c, 0, 0, 0);
}

// ---------------- prep ----------------
// wq: [t<24][kt<4][lane<64][j<8]  = bf16(qkv_w[t*16+(l&15)][kt*32+(l>>4)*8+j])
// wp: [t<8 ][kt<4][lane<64][j<8]  = bf16(proj_w[...same...])
// b2: [h<4][t<16][ln<64][r<4] f32 = bias*log2e at query n=16*(t>>2)+(ln&15),
//     key m=16*(t&3)+4*(ln>>4)+r; 0 outside valid range. 64 KB, w-indep.
//     Used as the QK^T MFMA C-operand (S*log2e + b2, then exp2).
// maskq: [w<64][ln<64] uint2; bit t*4+r = (key valid AND not masked).
__global__ void prep_kernel(const float* __restrict__ mask,
                            const float* __restrict__ qkv_w,
                            const float* __restrict__ proj_w,
                            const float* __restrict__ bias_table,
                            bf16_t* __restrict__ wq,
                            bf16_t* __restrict__ wp,
                            float* __restrict__ b2,
                            uint2* __restrict__ maskq) {
  const int stride = gridDim.x * blockDim.x;
  const int tid0 = blockIdx.x * blockDim.x + threadIdx.x;
  for (int i = tid0; i < 24 * 4 * 64 * 8; i += stride) {
    int j = i & 7, l = (i >> 3) & 63, kt = (i >> 9) & 3, t = i >> 11;
    int n = t * 16 + (l & 15), k = kt * 32 + (l >> 4) * 8 + j;
    wq[i] = (bf16_t)qkv_w[n * 128 + k];
  }
  for (int i = tid0; i < 8 * 4 * 64 * 8; i += stride) {
    int j = i & 7, l = (i >> 3) & 63, kt = (i >> 9) & 3, t = i >> 11;
    int n = t * 16 + (l & 15), k = kt * 32 + (l >> 4) * 8 + j;
    wp[i] = (bf16_t)proj_w[n * 128 + k];
  }
  for (int i = tid0; i < 4 * 16 * 64 * 4; i += stride) {
    int r = i & 3, ln = (i >> 2) & 63, t = (i >> 8) & 15, h = i >> 12;
    int n = (t >> 2) * 16 + (ln & 15);
    int m = (t & 3) * 16 + (ln >> 4) * 4 + r;
    float v = 0.0f;
    if (n < 49 && m < 49) {
      int cn = 13 * (n / 7) + n % 7;
      int mm = 48 - m;
      int cm = 13 * (mm / 7) + mm % 7;
      v = bias_table[(cn + cm) * 4 + h] * LOG2E;
    }
    b2[i] = v;
  }
  for (int i = tid0; i < 64 * 64; i += stride) {
    int ln = i & 63, w = i >> 6;
    unsigned lo = 0, hi = 0;
    for (int t = 0; t < 16; ++t) {
      int n = (t >> 2) * 16 + (ln & 15);
      for (int r = 0; r < 4; ++r) {
        int m = (t & 3) * 16 + (ln >> 4) * 4 + r;
        bool on = (m < 49) && (n >= 49 || mask[(w * 49 + n) * 49 + m] > -50.0f);
        int bit = t * 4 + r;
        if (on) { if (bit < 32) lo |= 1u << bit; else hi |= 1u << (bit - 32); }
      }
    }
    maskq[i] = make_uint2(lo, hi);
  }
}

// ---------------- fused window MSA ----------------
__global__ __launch_bounds__(256, 4) void msa_kernel(
    const float* __restrict__ x,
    const float* __restrict__ qkv_b,
    const float* __restrict__ proj_b,
    const bf16_t* __restrict__ wq,
    const bf16_t* __restrict__ wp,
    const float* __restrict__ b2,
    const uint2* __restrict__ maskq,
    float* __restrict__ out) {
  // gA (16,384 B): As[64][128] bf16, 16B-block XOR-swizzle by (row&7)
  //   [conflict-free]. After barrier-2 aliased by per-head V^T[32][64]
  //   (16B-block XOR by d&7) [conflict-free]; V^T stays live through PV.
  // gT (4 x 5,120 B wave-private slabs): [64][40] padded, NO xor -- 80B row
  //   stride puts 16-row accesses on 8 distinct 16B slots (2-deep = free).
  //   Hosts, in order, K -> Q -> P(half0) -> P(half1) -> O. Proj reads all
  //   4 slabs after barrier-3.
  // Total 36,864 B => 4 blocks/CU.
  __shared__ __align__(16) bf16_t gA[8192];
  __shared__ __align__(16) bf16_t gT[4][2560];

#define VTP(hh, d, c) (gA + (hh) * 2048 + (d) * 64 + (((((c) >> 3) ^ ((d) & 7))) << 3) + ((c) & 7))
#define TTP(hh, row, c) (gT[hh] + (row) * 40 + (c))

  const int tid = threadIdx.x;
  const int wv  = tid >> 6;   // wave 0..3 == head
  const int ln  = tid & 63;
  const int l16 = ln & 15;
  const int l4  = ln >> 4;    // 0..3
  const int b   = blockIdx.x;
  const int w   = b & 63;     // mask window index
  const int h   = wv;

  // mask bits for this lane's (query,key) fragment positions — issue early.
  const uint2 mq = maskq[(w << 6) | ln];

  // ---- Phase 1: x -> As (bf16, swizzled), 16B writes, zero pad rows ----
  {
    const float4* xb = (const float4*)(x + (size_t)b * (49 * 128));
#pragma unroll
    for (int j = 0; j < 4; ++j) {
      int idx = j * 256 + tid;      // 0..1023
      int row = idx >> 4;
      int c8  = idx & 15;
      bf8v o;
      if (row < 49) {
        float4 u0 = xb[row * 32 + c8 * 2];
        float4 u1 = xb[row * 32 + c8 * 2 + 1];
        o = (bf8v){ (bf16_t)u0.x, (bf16_t)u0.y, (bf16_t)u0.z, (bf16_t)u0.w,
                    (bf16_t)u1.x, (bf16_t)u1.y, (bf16_t)u1.z, (bf16_t)u1.w };
      } else {
        o = (bf8v){ (bf16_t)0.f, (bf16_t)0.f, (bf16_t)0.f, (bf16_t)0.f,
                    (bf16_t)0.f, (bf16_t)0.f, (bf16_t)0.f, (bf16_t)0.f };
      }
      *(bf8v*)(gA + row * 128 + ((c8 ^ (row & 7)) << 3)) = o;
    }
  }
  __syncthreads();

  // ---- pass 1 (SWAPPED): Q^T_h, K^T_h = W @ X^T  (acc rows = channels) ----
  f4v acc[4][4];   // [ti: 0,1 = Q d-tiles; 2,3 = K d-tiles][mt]
#pragma unroll
  for (int ti = 0; ti < 4; ++ti)
#pragma unroll
    for (int mt = 0; mt < 4; ++mt) acc[ti][mt] = (f4v){0.f, 0.f, 0.f, 0.f};
#pragma unroll
  for (int kt = 0; kt < 4; ++kt) {
    bf8v bb[4];
#pragma unroll
    for (int ti = 0; ti < 4; ++ti) {
      int t = (ti < 2) ? (2 * h + ti) : (8 + 2 * h + (ti - 2));
      bb[ti] = *(const bf8v*)(wq + (((t * 4 + kt) * 64 + ln) << 3));
    }
    __builtin_amdgcn_s_setprio(1);
#pragma unroll
    for (int mt = 0; mt < 4; ++mt) {
      int row = mt * 16 + l16;
      bf8v a = *(const bf8v*)(gA + row * 128 + ((((4 * kt + l4)) ^ (row & 7)) << 3));
#pragma unroll
      for (int ti = 0; ti < 4; ++ti)
        acc[ti][mt] = mfma16(bb[ti], a, acc[ti][mt]);
    }
    __builtin_amdgcn_s_setprio(0);
  }

  // ---- K epilogue: transposed b64 stores -> K[tok][d]; kf frags ----
  bf8v kf[4], qf[4];
#pragma unroll
  for (int ti = 0; ti < 2; ++ti) {
    float4 kb = *(const float4*)(qkv_b + 128 + 32 * h + 16 * ti + 4 * l4);
#pragma unroll
    for (int mt = 0; mt < 4; ++mt) {
      f4v v = acc[2 + ti][mt];
      bf4v o = { (bf16_t)(v[0] + kb.x), (bf16_t)(v[1] + kb.y),
                 (bf16_t)(v[2] + kb.z), (bf16_t)(v[3] + kb.w) };
      *(bf4v*)TTP(h, mt * 16 + l16, ti * 16 + 4 * l4) = o;
    }
  }
#pragma unroll
  for (int mt = 0; mt < 4; ++mt)
    kf[mt] = *(const bf8v*)TTP(h, mt * 16 + l16, 8 * l4);

  // ---- Q epilogue (overwrites K copy; in-wave DS order); exp2-domain scale ----
#pragma unroll
  for (int ti = 0; ti < 2; ++ti) {
    float4 qb = *(const float4*)(qkv_b + 32 * h + 16 * ti + 4 * l4);
#pragma unroll
    for (int mt = 0; mt < 4; ++mt) {
      f4v v = acc[ti][mt];
      bf4v o = { (bf16_t)((v[0] + qb.x) * QK_SCALE_LOG2E),
                 (bf16_t)((v[1] + qb.y) * QK_SCALE_LOG2E),
                 (bf16_t)((v[2] + qb.z) * QK_SCALE_LOG2E),
                 (bf16_t)((v[3] + qb.w) * QK_SCALE_LOG2E) };
      *(bf4v*)TTP(h, mt * 16 + l16, ti * 16 + 4 * l4) = o;
    }
  }
#pragma unroll
  for (int mt = 0; mt < 4; ++mt)
    qf[mt] = *(const bf8v*)TTP(h, mt * 16 + l16, 8 * l4);

  // ---- pass 2: V_h, UNSWAPPED (acc rows = tokens, matches V^T epilogue) ----
  f4v vacc[2][4];
#pragma unroll
  for (int ti = 0; ti < 2; ++ti)
#pragma unroll
    for (int mt = 0; mt < 4; ++mt) vacc[ti][mt] = (f4v){0.f, 0.f, 0.f, 0.f};
#pragma unroll
  for (int kt = 0; kt < 4; ++kt) {
    bf8v bb2[2];
#pragma unroll
    for (int ti = 0; ti < 2; ++ti) {
      int t = 16 + 2 * h + ti;
      bb2[ti] = *(const bf8v*)(wq + (((t * 4 + kt) * 64 + ln) << 3));
    }
    __builtin_amdgcn_s_setprio(1);
#pragma unroll
    for (int mt = 0; mt < 4; ++mt) {
      int row = mt * 16 + l16;
      bf8v a = *(const bf8v*)(gA + row * 128 + ((((4 * kt + l4)) ^ (row & 7)) << 3));
#pragma unroll
      for (int ti = 0; ti < 2; ++ti)
        vacc[ti][mt] = mfma16(a, bb2[ti], vacc[ti][mt]);   // X as A => rows=tok
    }
    __builtin_amdgcn_s_setprio(0);
  }

  __syncthreads();   // barrier-2: all As reads done -> V^T may alias gA

  // ---- V^T epilogue: V^T[d = ti*16+l16][tok = mt*16+4*l4+r], b64 stores ----
#pragma unroll
  for (int ti = 0; ti < 2; ++ti) {
    float bias = qkv_b[256 + 32 * h + ti * 16 + l16];
#pragma unroll
    for (int mt = 0; mt < 4; ++mt) {
      bf4v o = { (bf16_t)(vacc[ti][mt][0] + bias), (bf16_t)(vacc[ti][mt][1] + bias),
                 (bf16_t)(vacc[ti][mt][2] + bias), (bf16_t)(vacc[ti][mt][3] + bias) };
      *(bf4v*)VTP(h, ti * 16 + l16, mt * 16 + 4 * l4) = o;
    }
  }

  // ---- QK^T + softmax in two key-halves; bias preloaded as MFMA C-init ----
  // lane (l4,l16) reg r = P[query=16nt+l16][key=16mtk+4l4+r]
  const f4v* b2h = (const f4v*)(b2 + ((size_t)h << 12));   // [t][ln] f4v
  bf4v pk[2][4];                                  // packed half-1 P (bf16)
#pragma unroll
  for (int half = 0; half < 2; ++half) {
    f4v lgh[2][4];
    // C-init = bias*log2e (loads issue while kf/qf settle)
#pragma unroll
    for (int mtk2 = 0; mtk2 < 2; ++mtk2)
#pragma unroll
      for (int nt = 0; nt < 4; ++nt)
        lgh[mtk2][nt] = b2h[((nt * 4 + half * 2 + mtk2) << 6) | ln];
    __builtin_amdgcn_s_setprio(1);
#pragma unroll
    for (int mtk2 = 0; mtk2 < 2; ++mtk2)
#pragma unroll
      for (int nt = 0; nt < 4; ++nt)
        lgh[mtk2][nt] = mfma16(kf[half * 2 + mtk2], qf[nt], lgh[mtk2][nt]);
    __builtin_amdgcn_s_setprio(0);
#pragma unroll
    for (int nt = 0; nt < 4; ++nt) {
#pragma unroll
      for (int mtk2 = 0; mtk2 < 2; ++mtk2) {
        const int t = nt * 4 + half * 2 + mtk2;
        unsigned bits = (t < 8) ? (mq.x >> (4 * t)) : (mq.y >> (4 * t - 32));
        f4v p;
        p[0] = (bits & 1u) ? __builtin_amdgcn_exp2f(lgh[mtk2][nt][0]) : 0.f;
        p[1] = (bits & 2u) ? __builtin_amdgcn_exp2f(lgh[mtk2][nt][1]) : 0.f;
        p[2] = (bits & 4u) ? __builtin_amdgcn_exp2f(lgh[mtk2][nt][2]) : 0.f;
        p[3] = (bits & 8u) ? __builtin_amdgcn_exp2f(lgh[mtk2][nt][3]) : 0.f;
        bf4v o = { (bf16_t)p[0], (bf16_t)p[1], (bf16_t)p[2], (bf16_t)p[3] };
        if (half == 0)
          *(bf4v*)TTP(h, nt * 16 + l16, mtk2 * 16 + 4 * l4) = o;   // over Q
        else
          pk[mtk2][nt] = o;
      }
    }
  }

  // ---- PV (SWAPPED): O^T = V^T @ P^T ; s = 1 @ P^T ; two key-halves ----
  const bf16_t one16 = (bf16_t)1.0f;
  const bf8v ones = { one16, one16, one16, one16, one16, one16, one16, one16 };
  f4v oc[2][4], sacc[4];
#pragma unroll
  for (int nt = 0; nt < 4; ++nt) {
    sacc[nt] = (f4v){0.f, 0.f, 0.f, 0.f};
#pragma unroll
    for (int dt = 0; dt < 2; ++dt) oc[dt][nt] = (f4v){0.f, 0.f, 0.f, 0.f};
  }
  {
    bf8v pf[4], vf[2];
#pragma unroll
    for (int nt = 0; nt < 4; ++nt) pf[nt] = *(const bf8v*)TTP(h, nt * 16 + l16, 8 * l4);
#pragma unroll
    for (int dt = 0; dt < 2; ++dt) vf[dt] = *(const bf8v*)VTP(h, dt * 16 + l16, 8 * l4);
    __builtin_amdgcn_s_setprio(1);
#pragma unroll
    for (int dt = 0; dt < 2; ++dt)
#pragma unroll
      for (int nt = 0; nt < 4; ++nt) oc[dt][nt] = mfma16(vf[dt], pf[nt], oc[dt][nt]);
#pragma unroll
    for (int nt = 0; nt < 4; ++nt) sacc[nt] = mfma16(ones, pf[nt], sacc[nt]);
    __builtin_amdgcn_s_setprio(0);
    // stage P half-1 over T (Q/P0 already consumed; in-wave DS order)
#pragma unroll
    for (int nt = 0; nt < 4; ++nt)
#pragma unroll
      for (int mtk2 = 0; mtk2 < 2; ++mtk2)
        *(bf4v*)TTP(h, nt * 16 + l16, mtk2 * 16 + 4 * l4) = pk[mtk2][nt];
#pragma unroll
    for (int nt = 0; nt < 4; ++nt) pf[nt] = *(const bf8v*)TTP(h, nt * 16 + l16, 8 * l4);
#pragma unroll
    for (int dt = 0; dt < 2; ++dt) vf[dt] = *(const bf8v*)VTP(h, dt * 16 + l16, 32 + 8 * l4);
    __builtin_amdgcn_s_setprio(1);
#pragma unroll
    for (int dt = 0; dt < 2; ++dt)
#pragma unroll
      for (int nt = 0; nt < 4; ++nt) oc[dt][nt] = mfma16(vf[dt], pf[nt], oc[dt][nt]);
#pragma unroll
    for (int nt = 0; nt < 4; ++nt) sacc[nt] = mfma16(ones, pf[nt], sacc[nt]);
    __builtin_amdgcn_s_setprio(0);
  }

  // ---- normalize + transposed b64 store: O[tok][d] into own gT slab ----
#pragma unroll
  for (int nt = 0; nt < 4; ++nt) {
    float inv = 1.0f / sacc[nt][0];
#pragma unroll
    for (int dt = 0; dt < 2; ++dt) {
      f4v v = oc[dt][nt];
      bf4v o = { (bf16_t)(v[0] * inv), (bf16_t)(v[1] * inv),
                 (bf16_t)(v[2] * inv), (bf16_t)(v[3] * inv) };
      *(bf4v*)TTP(h, nt * 16 + l16, dt * 16 + 4 * l4) = o;
    }
  }

  __syncthreads();   // barrier-3: O slabs -> proj

  // ---- proj GEMM (SWAPPED): rows = channels => float4 output stores ----
  {
    f4v pacc[4][2];   // [mt(token tile)][nj]; reg r = channel 4*l4+r within t
#pragma unroll
    for (int mt = 0; mt < 4; ++mt)
#pragma unroll
      for (int nj = 0; nj < 2; ++nj) pacc[mt][nj] = (f4v){0.f, 0.f, 0.f, 0.f};
#pragma unroll
    for (int kt = 0; kt < 4; ++kt) {
      bf8v bwv[2];
#pragma unroll
      for (int nj = 0; nj < 2; ++nj) {
        int t = wv * 2 + nj;
        bwv[nj] = *(const bf8v*)(wp + (((t * 4 + kt) * 64 + ln) << 3));
      }
      __builtin_amdgcn_s_setprio(1);
#pragma unroll
      for (int mt = 0; mt < 4; ++mt) {
        bf8v a = *(const bf8v*)TTP(kt, mt * 16 + l16, 8 * l4);
#pragma unroll
        for (int nj = 0; nj < 2; ++nj)
          pacc[mt][nj] = mfma16(bwv[nj], a, pacc[mt][nj]);   // W as A => rows=chan
      }
      __builtin_amdgcn_s_setprio(0);
    }
    float* ob = out + (size_t)b * (49 * 128);
#pragma unroll
    for (int nj = 0; nj < 2; ++nj) {
      int c0 = (wv * 2 + nj) * 16 + 4 * l4;
      float4 pb4 = *(const float4*)(proj_b + c0);
#pragma unroll
      for (int mt = 0; mt < 4; ++mt) {
        int tok = mt * 16 + l16;
        if (tok < 49) {
          f4v v = pacc[mt][nj];
          float4 o = make_float4(v[0] + pb4.x, v[1] + pb4.y,
                                 v[2] + pb4.z, v[3] + pb4.w);
          *(float4*)(ob + tok * 128 + c0) = o;
        }
      }
    }
  }
}

extern "C" void kernel_launch(void* const* d_in, const int* in_sizes, int n_in,
                              void* d_out, int out_size, void* d_ws, size_t ws_size,
                              hipStream_t stream) {
  const float* x          = (const float*)d_in[0];
  const float* mask       = (const float*)d_in[1];
  const float* qkv_w      = (const float*)d_in[2];
  const float* qkv_b      = (const float*)d_in[3];
  const float* proj_w     = (const float*)d_in[4];
  const float* proj_b     = (const float*)d_in[5];
  const float* bias_table = (const float*)d_in[6];

  char* ws = (char*)d_ws;
  bf16_t* wq    = (bf16_t*)ws;                    // 24*4*64*8 bf16 = 98304 B
  bf16_t* wp    = (bf16_t*)(ws + 98304);          // 8*4*64*8 bf16  = 32768 B
  float*  b2    = (float*)(ws + 131072);          // 4*16*64*4 f32  = 65536 B
  uint2*  maskq = (uint2*)(ws + 196608);          // 64*64 uint2    = 32768 B

  prep_kernel<<<1024, 256, 0, stream>>>(mask, qkv_w, proj_w, bias_table,
                                        wq, wp, b2, maskq);
  msa_kernel<<<4096, 256, 0, stream>>>(x, qkv_b, proj_b, wq, wp, b2, maskq,
                                       (float*)d_out);
}